// Round 3
// baseline (613.459 us; speedup 1.0000x reference)
//
#include <hip/hip_runtime.h>

// VQEmbedding forward (TRAINING=True):
//   z_e_x [32,256,64,64] f32, codebook [512,256] f32, labels [32] i32
//   out = concat(z_q_x, z_q_x_bar), each [32,256,64,64] f32 — both equal
//   codebook[argmin] in the forward pass.
//
// Reference arithmetic emulated bit-exactly (same as prior passing rounds):
//   - dot: ascending-d fp32 FMA chain per (point, code)  (== sgemm)
//   - in_sqr: fp64 ascending-d fma -> fp32
//   - cb_sqr: fp64 LDS-tree -> fp32 (identical tree to prior prep)
//   - dist = fmaf(-2, acc, fl(insq + cbs_k)); strict < ascending k == first-index tie
//
// R6 restructure (fixes R5's latency-bound 201 µs @ 24% VALUBusy):
//   - x tile [16 d][128 pts] staged in LDS via global_load_lds (16 B/lane),
//     double-buffered -> z read ONCE per block (was 8x), inner loop has no
//     global-load dependence.
//   - codebook packed per class, padded to 64 codes: cbP[cls][d][64]; wave w
//     owns codes [8w,8w+8) -> ONE aligned s_load_dwordx8 per d-step (SGPR
//     operands). Pad slots: cb=0, cbs=+inf -> never win argmin (no branches).
//   - xsq computed only by wave 0 (its lanes already read all 128 points).
//   - 512 thr/block, VGPR<=64, LDS 25.5 KB -> 4 blocks/CU = 100% occupancy.

#define D        256
#define KCODES   512
#define HW       4096
#define BATCH    32
#define NPTS     (BATCH * HW)      // 131072
#define NCLS     10
#define KPAD     64                // padded codes per class
#define NWAVES   8
#define WPW      8                 // codes per wave (8*8 = 64 = KPAD)
#define PTS      128               // points per block (2 per lane)
#define DC       16                // d-chunk staged per barrier
#define NCHUNK   (D / DC)          // 16

__constant__ int c_cls_start[11] = {0, 51, 101, 151, 201, 251, 301, 352, 402, 452, 502};

// Pack cbP[cls][d][j] = cb[c0+j][d] (0 for pad); cbsP pad slots = +inf.
__global__ __launch_bounds__(256) void prep_pack(const float* __restrict__ cb,
                                                 float* __restrict__ cbP,
                                                 float* __restrict__ cbsP) {
    const int cls = blockIdx.x;   // 0..9
    const int t   = threadIdx.x;  // 0..255
    const int c0  = c_cls_start[cls];
    const int cnt = c_cls_start[cls + 1] - c0;   // 50 or 51
#pragma unroll 4
    for (int i = 0; i < (D * KPAD) / 256; ++i) {  // 64 iters
        int idx = i * 256 + t;
        int d = idx >> 6, j = idx & 63;
        float v = (j < cnt) ? cb[(size_t)(c0 + j) * D + d] : 0.0f;
        cbP[((size_t)cls * D + d) * KPAD + j] = v;   // coalesced writes
    }
    if (t < KPAD && t >= cnt) cbsP[cls * KPAD + t] = __builtin_inff();
}

// cbs valid slots: fp64 LDS tree (identical arithmetic to prior passing prep).
__global__ __launch_bounds__(256) void prep_sq(const float* __restrict__ cb,
                                               float* __restrict__ cbsP) {
    const int k = blockIdx.x;            // 0..511
    if (k >= 502) return;                // shared keys: masked out in training
    int cls = 0;
    while (k >= c_cls_start[cls + 1]) ++cls;
    const int j = k - c_cls_start[cls];
    const int d = threadIdx.x;
    float v = cb[(size_t)k * D + d];
    __shared__ double red[256];
    red[d] = (double)v * (double)v;
    __syncthreads();
    for (int s = 128; s > 0; s >>= 1) {
        if (d < s) red[d] += red[d + s];
        __syncthreads();
    }
    if (d == 0) cbsP[cls * KPAD + j] = (float)red[0];
}

__global__ __launch_bounds__(512, 8) void vq_kernel(const float* __restrict__ z,
                                                    const int* __restrict__ labels,
                                                    const float* __restrict__ cbP,
                                                    const float* __restrict__ cbsP,
                                                    float* __restrict__ out) {
    const int lane = threadIdx.x & 63;
    const int w    = __builtin_amdgcn_readfirstlane(threadIdx.x >> 6);  // wave 0..7
    const int b    = blockIdx.x >> 5;                 // 32 blocks per image
    const int hw0  = (blockIdx.x & 31) << 7;          // 128-point tile base
    const int p2   = hw0 | (lane << 1);               // this lane's 2 points
    const int lab  = __builtin_amdgcn_readfirstlane(labels[b]);
    const int jbase = w * WPW;                        // local code base (SGPR)

    const float* __restrict__ cbw = cbP + (size_t)lab * D * KPAD + jbase;
    const float* __restrict__ zb  = z + (size_t)b * D * HW + hw0;

    __shared__ float bufX[2][DC][PTS];   // 16 KB
    __shared__ float insq[PTS];          // 0.5 KB
    __shared__ float sd[NWAVES][PTS];    // 4 KB
    __shared__ int   si[NWAVES][PTS];    // 4 KB
    __shared__ int   fidx[PTS];          // 0.5 KB

    // Cooperative staging: wave w stages rows {2w, 2w+1} of a 16-row chunk.
    // LDS dest is wave-uniform base + lane*16 (linear) per global_load_lds rules.
    const int srow = 2 * w + (lane >> 5);       // row within chunk
    const int scol = (lane & 31) << 2;          // float col within row
    auto STAGE = [&](int pb, int c) {
        const float* g = zb + (size_t)(c * DC + srow) * HW + scol;
        __builtin_amdgcn_global_load_lds(
            (const __attribute__((address_space(1))) void*)g,
            (__attribute__((address_space(3))) void*)&bufX[pb][2 * w][0],
            16, 0, 0);
    };

    float acc[WPW][2];
#pragma unroll
    for (int j = 0; j < WPW; ++j) { acc[j][0] = 0.0f; acc[j][1] = 0.0f; }
    double xsq0 = 0.0, xsq1 = 0.0;   // wave 0 only: ||x||^2, ascending d

    STAGE(0, 0);
    __syncthreads();   // compiler drains vmcnt before barrier -> chunk 0 ready

    for (int c = 0; c < NCHUNK; ++c) {
        const int pb = c & 1;
        if (c + 1 < NCHUNK) STAGE(pb ^ 1, c + 1);   // prefetch next chunk
        const float* __restrict__ cbc = cbw + (size_t)(c * DC) * KPAD;
#pragma unroll
        for (int dd = 0; dd < DC; ++dd) {
            const float2 x = *(const float2*)&bufX[pb][dd][lane << 1];  // ds_read_b64
            const float* __restrict__ cr = cbc + dd * KPAD;  // uniform -> s_load_dwordx8
            if (w == 0) {   // wave-uniform branch; lanes cover all 128 points
                xsq0 = fma((double)x.x, (double)x.x, xsq0);
                xsq1 = fma((double)x.y, (double)x.y, xsq1);
            }
#pragma unroll
            for (int j = 0; j < WPW; ++j) {
                const float cv = cr[j];
                acc[j][0] = fmaf(x.x, cv, acc[j][0]);   // ascending-d fp32 chain
                acc[j][1] = fmaf(x.y, cv, acc[j][1]);
            }
        }
        __syncthreads();   // next chunk staged + this buffer free for reuse
    }

    if (w == 0) {
        float2 iq = make_float2((float)xsq0, (float)xsq1);
        *(float2*)&insq[lane << 1] = iq;
    }
    __syncthreads();

    // Emulated reference distance; local argmin over this wave's 8 codes.
    // Pad slots: cbs=+inf -> dist=+inf -> never selected by strict <.
    const float* __restrict__ csq = cbsP + lab * KPAD + jbase;  // uniform
    const float2 iq = *(const float2*)&insq[lane << 1];
    float best0 = __builtin_inff(), best1 = __builtin_inff();
    int bi0 = jbase, bi1 = jbase;
#pragma unroll
    for (int j = 0; j < WPW; ++j) {
        const float cs = csq[j];
        float T0 = iq.x + cs;                       // fp32 add, RNE
        float v0 = fmaf(-2.0f, acc[j][0], T0);      // == fl(T - 2*acc)
        if (v0 < best0) { best0 = v0; bi0 = jbase + j; }
        float T1 = iq.y + cs;
        float v1 = fmaf(-2.0f, acc[j][1], T1);
        if (v1 < best1) { best1 = v1; bi1 = jbase + j; }
    }
    sd[w][(lane << 1) + 0] = best0;  si[w][(lane << 1) + 0] = bi0;
    sd[w][(lane << 1) + 1] = best1;  si[w][(lane << 1) + 1] = bi1;
    __syncthreads();

    // Cross-wave argmin (ascending w + strict < == lowest-index tie-break).
    if (threadIdx.x < PTS) {
        const int pi = threadIdx.x;
        float fb = sd[0][pi];
        int   fi = si[0][pi];
#pragma unroll
        for (int w2 = 1; w2 < NWAVES; ++w2) {
            float dv = sd[w2][pi];
            if (dv < fb) { fb = dv; fi = si[w2][pi]; }
        }
        fidx[pi] = fi;   // local code index within class (valid by construction)
    }
    __syncthreads();

    // Epilogue: out0 = out1 = cbP[lab][d][fidx]; wave w writes d in [32w,32w+32),
    // each lane stores its 2 points as dwordx2 per output per d.
    const int j0 = fidx[(lane << 1) + 0];
    const int j1 = fidx[(lane << 1) + 1];
    float* __restrict__ o0 = out + (size_t)b * (D * HW) + p2;
    float* __restrict__ o1 = o0 + (size_t)NPTS * D;
    const int d0 = w * (D / NWAVES);   // 32 d per wave
    const float* __restrict__ crow = cbP + ((size_t)lab * D + d0) * KPAD;
    for (int d = d0; d < d0 + D / NWAVES; ++d) {
        float2 v;                      // gathers within a 256 B row -> L1
        v.x = crow[j0];
        v.y = crow[j1];
        *(float2*)(o0 + (size_t)d * HW) = v;
        *(float2*)(o1 + (size_t)d * HW) = v;
        crow += KPAD;
    }
}

extern "C" void kernel_launch(void* const* d_in, const int* in_sizes, int n_in,
                              void* d_out, int out_size, void* d_ws, size_t ws_size,
                              hipStream_t stream) {
    const float* z      = (const float*)d_in[0];
    const float* cb     = (const float*)d_in[1];
    const int*   labels = (const int*)d_in[2];
    float* out = (float*)d_out;

    float* cbP  = (float*)d_ws;                        // 10*256*64 f32 = 640 KB
    float* cbsP = cbP + (size_t)NCLS * D * KPAD;       // 640 f32

    hipLaunchKernelGGL(prep_pack, dim3(NCLS), dim3(256), 0, stream, cb, cbP, cbsP);
    hipLaunchKernelGGL(prep_sq, dim3(KCODES), dim3(256), 0, stream, cb, cbsP);
    hipLaunchKernelGGL(vq_kernel, dim3(NPTS / PTS), dim3(512), 0, stream,
                       z, labels, cbP, cbsP, out);
}

// Round 5
// 397.651 us; speedup vs baseline: 1.5427x; 1.5427x over previous
//
#include <hip/hip_runtime.h>

// VQEmbedding forward (TRAINING=True):
//   z_e_x [32,256,64,64] f32, codebook [512,256] f32, labels [32] i32
//   out = concat(z_q_x, z_q_x_bar), each [32,256,64,64] f32 — both equal
//   codebook[argmin] in the forward pass (x+(c-x) roundoff ~4e-7 << thr).
//
// Reference arithmetic emulated bit-exactly (passing since Round 2 of the
// prior session):
//   - dot: ascending-d fp32 FMA chain per (point, code)  (== sgemm)
//   - in_sqr: fp64 ascending-d fma -> fp32
//   - cb_sqr: fp64 LDS tree -> fp32
//   - dist = fmaf(-2, acc, fl(insq + cbs_k)); strict < ascending k == first tie
//
// Structure = the measured-best R0 kernel (vq ~146 us): block = 4 waves / 64
// points; wave w handles 13 codes (wave-uniform kbase -> SGPR operands) for
// all 64 points. 2048 blocks x 4 waves = 8192 waves = 100% occupancy. LDS
// combine (2 KB) for the cross-wave argmin. Restructures measured WORSE:
// R5 (8 waves, 2pt/lane, dwordx2): vq 201 us; R6 (LDS-staged x, packed cb):
// vq 338 us with 3.3x HBM write amplification. Reverted.
//
// R7/R8 delta (only change vs R0): nontemporal output stores. out is 268 MB
// of write-once data; NT bypasses L2 allocate so the x4-reused z reads and
// the cbT gather rows keep L2 residency (that reuse absorption is what makes
// this structure fastest: R5 measured FETCH 107 MB < 134 MB logical).
// (R4-round bench was an infra failure — container died; resubmitting.)

#define D       256
#define KCODES  512
#define HW      4096
#define BATCH   32
#define NPTS    (BATCH * HW)   // 131072
#define WPW     13             // codes per wave (4*13=52 >= max class size 51)

__constant__ int c_cls_start[11] = {0, 51, 101, 151, 201, 251, 301, 352, 402, 452, 502};

// Prep: cbT[d][k] = cb[k][d]  (per-d class slice contiguous -> scalar loads),
//       cbs[k] = fl32( fp64 sum_d cb[k][d]^2 )
__global__ __launch_bounds__(256) void prep_kernel(const float* __restrict__ cb,
                                                   float* __restrict__ cbT,
                                                   float* __restrict__ cbs) {
    const int k = blockIdx.x;   // 0..511
    const int d = threadIdx.x;  // 0..255
    float v = cb[k * D + d];
    cbT[(size_t)d * KCODES + k] = v;
    __shared__ double red[256];
    red[d] = (double)v * (double)v;
    __syncthreads();
    for (int s = 128; s > 0; s >>= 1) {
        if (d < s) red[d] += red[d + s];
        __syncthreads();
    }
    if (d == 0) cbs[k] = (float)red[0];
}

__global__ __launch_bounds__(256) void vq_kernel(const float* __restrict__ z,
                                                 const int* __restrict__ labels,
                                                 const float* __restrict__ cbT,
                                                 const float* __restrict__ cbs,
                                                 float* __restrict__ out) {
    const int lane = threadIdx.x & 63;
    const int w    = __builtin_amdgcn_readfirstlane(threadIdx.x >> 6);  // wave id 0..3
    const int b    = blockIdx.x >> 6;                  // 64 blocks per image
    const int hw   = ((blockIdx.x & 63) << 6) | lane;  // this lane's point
    const int lab  = __builtin_amdgcn_readfirstlane(labels[b]);
    const int c0   = c_cls_start[lab];
    const int cnt  = c_cls_start[lab + 1] - c0;        // 50 or 51
    const int kbase = c0 + w * WPW;                    // wave-uniform (SGPR)
    const int myn   = min(WPW, cnt - w * WPW);         // 13,13,13,{11|12}

    const float* __restrict__ xp = z + (size_t)b * (D * HW) + hw;  // x[d] = xp[d*HW]

    float acc[WPW];
#pragma unroll
    for (int j = 0; j < WPW; ++j) acc[j] = 0.0f;

    double xsq = 0.0;  // ||x||^2 in fp64, ascending d

    // x prefetch pipeline, depth 4
    float xb[4];
#pragma unroll
    for (int i = 0; i < 4; ++i) xb[i] = xp[(size_t)i * HW];

    for (int d = 0; d < D; d += 4) {
        float xn[4];
#pragma unroll
        for (int i = 0; i < 4; ++i) {
            int dn = (d + 4 + i) & (D - 1);  // wrap on last chunk (harmless reload)
            xn[i] = xp[(size_t)dn * HW];
        }
#pragma unroll
        for (int i = 0; i < 4; ++i) {
            // wave-uniform address -> scalar loads, SGPR FMA operand
            const float* __restrict__ wd = cbT + (size_t)(d + i) * KCODES + kbase;
            const float x = xb[i];
            xsq = fma((double)x, (double)x, xsq);
#pragma unroll
            for (int j = 0; j < WPW; ++j)
                acc[j] = fmaf(x, wd[j], acc[j]);  // ascending-d fp32 chain == sgemm
        }
#pragma unroll
        for (int i = 0; i < 4; ++i) xb[i] = xn[i];
    }

    // Emulated reference distance; local argmin over this wave's codes
    const float insq = (float)xsq;
    float best = __builtin_inff();
    int bi = kbase;
#pragma unroll
    for (int j = 0; j < WPW; ++j) {
        if (j < myn) {
            float T    = insq + cbs[kbase + j];    // fp32 add, RNE
            float dist = fmaf(-2.0f, acc[j], T);   // == fl(T - 2*acc)
            if (dist < best) { best = dist; bi = kbase + j; }
        }
    }

    // Cross-wave argmin via LDS (ascending w + strict < == lowest-index tie-break)
    __shared__ float sd[4][64];
    __shared__ int   si[4][64];
    sd[w][lane] = best;
    si[w][lane] = bi;
    __syncthreads();
    float fb = sd[0][lane];
    int   fi = si[0][lane];
#pragma unroll
    for (int w2 = 1; w2 < 4; ++w2) {
        float dv = sd[w2][lane];
        if (dv < fb) { fb = dv; fi = si[w2][lane]; }
    }

    // Epilogue: out0 = out1 = codebook[fi]; wave w writes d in [64w, 64w+64).
    // Gathers stay cached (204 B class window -> L1/L2); stores are
    // nontemporal so the 268 MB write-once stream doesn't evict z/cbT from L2.
    float* __restrict__ o0 = out + (size_t)b * (D * HW) + hw;
    float* __restrict__ o1 = o0 + (size_t)NPTS * D;
    const int d0 = w * 64;
#pragma unroll 8
    for (int d = d0; d < d0 + 64; ++d) {
        float v = cbT[(size_t)d * KCODES + fi];
        __builtin_nontemporal_store(v, o0 + (size_t)d * HW);
        __builtin_nontemporal_store(v, o1 + (size_t)d * HW);
    }
}

extern "C" void kernel_launch(void* const* d_in, const int* in_sizes, int n_in,
                              void* d_out, int out_size, void* d_ws, size_t ws_size,
                              hipStream_t stream) {
    const float* z      = (const float*)d_in[0];
    const float* cb     = (const float*)d_in[1];
    const int*   labels = (const int*)d_in[2];
    float* out = (float*)d_out;

    float* cbT = (float*)d_ws;              // 256*512 f32 = 512 KB
    float* cbs = cbT + (size_t)D * KCODES;  // 512 f32

    hipLaunchKernelGGL(prep_kernel, dim3(KCODES), dim3(D), 0, stream, cb, cbT, cbs);
    hipLaunchKernelGGL(vq_kernel, dim3(NPTS / 64), dim3(256), 0, stream,
                       z, labels, cbT, cbs, out);
}

// Round 6
// 393.355 us; speedup vs baseline: 1.5596x; 1.0109x over previous
//
#include <hip/hip_runtime.h>

// VQEmbedding forward (TRAINING=True):
//   z_e_x [32,256,64,64] f32, codebook [512,256] f32, labels [32] i32
//   out = concat(z_q_x, z_q_x_bar), each [32,256,64,64] f32 — both equal
//   codebook[argmin] in the forward pass (x+(c-x) roundoff ~4e-7 << thr).
//
// Reference arithmetic emulated bit-exactly:
//   - dot: ascending-d fp32 FMA chain per (point, code)  (== sgemm)
//   - in_sqr: fp64 ascending-d fma -> fp32
//   - cb_sqr: fp64 LDS tree -> fp32
//   - dist = fmaf(-2, acc, fl(insq + cbs_k)); strict < ascending k == first tie
//
// Structure = measured-best R0: block = 4 waves / 64 points; wave w handles
// 13 codes (wave-uniform kbase -> SGPR operands) for all 64 points. 2048
// blocks x 4 waves = 100% occupancy. Restructures measured WORSE:
// R5 (8 waves, 2pt/lane): vq 201 us; R6 (LDS-staged x): vq 338 us, 3.3x WRITE.
// R7 (NT output stores): total 406.7 -> 397.7, kept.
//
// R9 delta: x prefetch pipeline deepened 4 -> 8 d-steps (two groups in
// flight). Load-to-use distance grows from ~130 to ~260 issue-cycles,
// covering L2-hit latency (~200 cyc) per-wave instead of relying on TLP.
// VGPR stays <= 64 (8 waves/SIMD preserved, enforced by launch_bounds).

#define D       256
#define KCODES  512
#define HW      4096
#define BATCH   32
#define NPTS    (BATCH * HW)   // 131072
#define WPW     13             // codes per wave (4*13=52 >= max class size 51)
#define PF      8              // prefetch depth (d-steps in flight)

__constant__ int c_cls_start[11] = {0, 51, 101, 151, 201, 251, 301, 352, 402, 452, 502};

// Prep: cbT[d][k] = cb[k][d]  (per-d class slice contiguous -> scalar loads),
//       cbs[k] = fl32( fp64 sum_d cb[k][d]^2 )
__global__ __launch_bounds__(256) void prep_kernel(const float* __restrict__ cb,
                                                   float* __restrict__ cbT,
                                                   float* __restrict__ cbs) {
    const int k = blockIdx.x;   // 0..511
    const int d = threadIdx.x;  // 0..255
    float v = cb[k * D + d];
    cbT[(size_t)d * KCODES + k] = v;
    __shared__ double red[256];
    red[d] = (double)v * (double)v;
    __syncthreads();
    for (int s = 128; s > 0; s >>= 1) {
        if (d < s) red[d] += red[d + s];
        __syncthreads();
    }
    if (d == 0) cbs[k] = (float)red[0];
}

__global__ __launch_bounds__(256, 8) void vq_kernel(const float* __restrict__ z,
                                                    const int* __restrict__ labels,
                                                    const float* __restrict__ cbT,
                                                    const float* __restrict__ cbs,
                                                    float* __restrict__ out) {
    const int lane = threadIdx.x & 63;
    const int w    = __builtin_amdgcn_readfirstlane(threadIdx.x >> 6);  // wave id 0..3
    const int b    = blockIdx.x >> 6;                  // 64 blocks per image
    const int hw   = ((blockIdx.x & 63) << 6) | lane;  // this lane's point
    const int lab  = __builtin_amdgcn_readfirstlane(labels[b]);
    const int c0   = c_cls_start[lab];
    const int cnt  = c_cls_start[lab + 1] - c0;        // 50 or 51
    const int kbase = c0 + w * WPW;                    // wave-uniform (SGPR)
    const int myn   = min(WPW, cnt - w * WPW);         // 13,13,13,{11|12}

    const float* __restrict__ xp = z + (size_t)b * (D * HW) + hw;  // x[d] = xp[d*HW]

    float acc[WPW];
#pragma unroll
    for (int j = 0; j < WPW; ++j) acc[j] = 0.0f;

    double xsq = 0.0;  // ||x||^2 in fp64, ascending d

    // x software pipeline, depth 8 (two 4-d groups in flight)
    float xb[PF];
#pragma unroll
    for (int i = 0; i < PF; ++i) xb[i] = xp[(size_t)i * HW];

    for (int d = 0; d < D; d += PF) {
        float xn[PF];
#pragma unroll
        for (int i = 0; i < PF; ++i) {
            int dn = (d + PF + i) & (D - 1);  // wrap on last chunk (harmless reload)
            xn[i] = xp[(size_t)dn * HW];
        }
#pragma unroll
        for (int i = 0; i < PF; ++i) {
            // wave-uniform address -> scalar loads, SGPR FMA operand
            const float* __restrict__ wd = cbT + (size_t)(d + i) * KCODES + kbase;
            const float x = xb[i];
            xsq = fma((double)x, (double)x, xsq);
#pragma unroll
            for (int j = 0; j < WPW; ++j)
                acc[j] = fmaf(x, wd[j], acc[j]);  // ascending-d fp32 chain == sgemm
        }
#pragma unroll
        for (int i = 0; i < PF; ++i) xb[i] = xn[i];
    }

    // Emulated reference distance; local argmin over this wave's codes
    const float insq = (float)xsq;
    float best = __builtin_inff();
    int bi = kbase;
#pragma unroll
    for (int j = 0; j < WPW; ++j) {
        if (j < myn) {
            float T    = insq + cbs[kbase + j];    // fp32 add, RNE
            float dist = fmaf(-2.0f, acc[j], T);   // == fl(T - 2*acc)
            if (dist < best) { best = dist; bi = kbase + j; }
        }
    }

    // Cross-wave argmin via LDS (ascending w + strict < == lowest-index tie-break)
    __shared__ float sd[4][64];
    __shared__ int   si[4][64];
    sd[w][lane] = best;
    si[w][lane] = bi;
    __syncthreads();
    float fb = sd[0][lane];
    int   fi = si[0][lane];
#pragma unroll
    for (int w2 = 1; w2 < 4; ++w2) {
        float dv = sd[w2][lane];
        if (dv < fb) { fb = dv; fi = si[w2][lane]; }
    }

    // Epilogue: out0 = out1 = codebook[fi]; wave w writes d in [64w, 64w+64).
    // Gathers stay cached (204 B class window -> L1/L2); stores are
    // nontemporal so the 268 MB write-once stream doesn't evict z/cbT from L2.
    float* __restrict__ o0 = out + (size_t)b * (D * HW) + hw;
    float* __restrict__ o1 = o0 + (size_t)NPTS * D;
    const int d0 = w * 64;
#pragma unroll 8
    for (int d = d0; d < d0 + 64; ++d) {
        float v = cbT[(size_t)d * KCODES + fi];
        __builtin_nontemporal_store(v, o0 + (size_t)d * HW);
        __builtin_nontemporal_store(v, o1 + (size_t)d * HW);
    }
}

extern "C" void kernel_launch(void* const* d_in, const int* in_sizes, int n_in,
                              void* d_out, int out_size, void* d_ws, size_t ws_size,
                              hipStream_t stream) {
    const float* z      = (const float*)d_in[0];
    const float* cb     = (const float*)d_in[1];
    const int*   labels = (const int*)d_in[2];
    float* out = (float*)d_out;

    float* cbT = (float*)d_ws;              // 256*512 f32 = 512 KB
    float* cbs = cbT + (size_t)D * KCODES;  // 512 f32

    hipLaunchKernelGGL(prep_kernel, dim3(KCODES), dim3(D), 0, stream, cb, cbT, cbs);
    hipLaunchKernelGGL(vq_kernel, dim3(NPTS / 64), dim3(256), 0, stream,
                       z, labels, cbT, cbs, out);
}